// Round 19
// baseline (755.543 us; speedup 1.0000x reference)
//
#include <hip/hip_runtime.h>
#include <hip/hip_bf16.h>

#define DD 4096
#define MM 4096
#define SS 2048
#define HH 32
#define HDD 128
#define NT 64  // BK=64 K-tiles

typedef unsigned short u16;
typedef unsigned int u32;
typedef __attribute__((ext_vector_type(8))) __bf16 bf16x8;
typedef __attribute__((ext_vector_type(4))) float f32x4;
typedef __attribute__((ext_vector_type(4))) float float4v;
typedef __attribute__((ext_vector_type(8))) unsigned short ushort8;
typedef __attribute__((ext_vector_type(4))) unsigned int uint4v;

__device__ __forceinline__ u16 f2bf(float f) {
  union { float f; unsigned u; } v; v.f = f;
  unsigned u = v.u;
  return (u16)((u + 0x7fffu + ((u >> 16) & 1u)) >> 16);
}
__device__ __forceinline__ float bf2f(u16 s) {
  union { unsigned u; float f; } v; v.u = ((unsigned)s) << 16;
  return v.f;
}
__device__ __forceinline__ f32x4 zero4() { f32x4 z = {0.f, 0.f, 0.f, 0.f}; return z; }

__device__ __forceinline__ void gl_lds16(const u16* g, u16* l) {
  __builtin_amdgcn_global_load_lds((__attribute__((address_space(1))) void*)(g),
                                   (__attribute__((address_space(3))) void*)(l), 16, 0, 0);
}

__device__ __forceinline__ unsigned cvtpk(float lo, float hi) {
  unsigned r;
  asm("v_cvt_pk_bf16_f32 %0, %1, %2" : "=v"(r) : "v"(lo), "v"(hi));
  return r;
}
__device__ __forceinline__ u16 cvt1(float v) {
  unsigned r;
  asm("v_cvt_pk_bf16_f32 %0, %1, %1" : "=v"(r) : "v"(v));
  return (u16)r;
}
__device__ __forceinline__ float exp2a(float x) {
  float r;
  asm("v_exp_f32 %0, %1" : "=v"(r) : "v"(x));
  return r;
}

// ---------------- merged prep: z<4 -> weight transpose+cvt; z==4 -> x f32->bf16 ----------------
__global__ __launch_bounds__(256) void k_prep(const float* __restrict__ x,
                                              const float* __restrict__ W0,
                                              const float* __restrict__ W1,
                                              const float* __restrict__ W2,
                                              const float* __restrict__ W3,
                                              u16* __restrict__ xb,
                                              u16* __restrict__ wt) {
  const int z = blockIdx.z;
  if (z == 4) {
    // x convert: 4096 blocks x 256 thr x 2 groups of 8
    int bid = blockIdx.y * 64 + blockIdx.x;
    int t = bid * 256 + (threadIdx.y * 64 + threadIdx.x);
#pragma unroll
    for (int s = 0; s < 2; ++s) {
      int i = t + s * 1048576;
      size_t o = (size_t)i * 8;
      float4v a = *(const float4v*)(x + o);
      float4v b = *(const float4v*)(x + o + 4);
      ushort8 v;
      v[0] = cvt1(a[0]); v[1] = cvt1(a[1]); v[2] = cvt1(a[2]); v[3] = cvt1(a[3]);
      v[4] = cvt1(b[0]); v[5] = cvt1(b[1]); v[6] = cvt1(b[2]); v[7] = cvt1(b[3]);
      *(ushort8*)(xb + o) = v;
    }
    return;
  }
  const float* W = z == 0 ? W0 : z == 1 ? W1 : z == 2 ? W2 : W3;
  u16* O = wt + (size_t)z * DD * DD;
  __shared__ u16 t[64][66];
  int k0 = blockIdx.x * 64, n0 = blockIdx.y * 64;
  int tx = threadIdx.x, ty = threadIdx.y;  // (64,4)
#pragma unroll
  for (int i = 0; i < 16; ++i) {
    int kk = ty + i * 4;
    t[tx][kk] = cvt1(W[(size_t)(k0 + kk) * DD + n0 + tx]);
  }
  __syncthreads();
  const int L = ty * 64 + tx;
  const int kx = L & 31, nb = L >> 5;
#pragma unroll
  for (int i = 0; i < 8; ++i) {
    int nn = nb + i * 8;
    u32 pk = *(const u32*)&t[nn][2 * kx];
    *(u32*)&O[(size_t)(n0 + nn) * DD + k0 + 2 * kx] = pk;
  }
}

#define BAR() __builtin_amdgcn_s_barrier()
#define LGKM0() asm volatile("s_waitcnt lgkmcnt(0)" ::: "memory")
#define LGKM8() asm volatile("s_waitcnt lgkmcnt(8)" ::: "memory")
#define VM6() asm volatile("s_waitcnt vmcnt(6)" ::: "memory")
#define VM0() asm volatile("s_waitcnt vmcnt(0)" ::: "memory")
#define PRIO1() __builtin_amdgcn_s_setprio(1)
#define PRIO0() __builtin_amdgcn_s_setprio(0)

// ---------------- 256x256 BK=64 deep-staged GEMM (r12/r17, 3-phase tiles) ----------------
#define MFMA16(QM, QN)                                                             \
  _Pragma("unroll") for (int kk = 0; kk < 2; ++kk)                                 \
  _Pragma("unroll") for (int mi = 0; mi < 4; ++mi)                                 \
  _Pragma("unroll") for (int ni = 0; ni < 2; ++ni)                                 \
      acc[(QM)*4 + mi][(QN)*2 + ni] = __builtin_amdgcn_mfma_f32_16x16x32_bf16(     \
          af[mi][kk], bf[(QN)*2 + ni][kk], acc[(QM)*4 + mi][(QN)*2 + ni], 0, 0, 0);

#define RDA2(P0, P1, QM)                                                           \
  _Pragma("unroll") for (int mi = 0; mi < 4; ++mi) {                               \
    af[mi][0] = *(const bf16x8*)((P0) + ((QM)*4 + mi) * 2048);                     \
    af[mi][1] = *(const bf16x8*)((P1) + ((QM)*4 + mi) * 2048);                     \
  }

#define RDB2(P0, P1, QN)                                                           \
  _Pragma("unroll") for (int ni = 0; ni < 2; ++ni) {                               \
    bf[(QN)*2 + ni][0] = *(const bf16x8*)((P0) + ((QN)*2 + ni) * 2048);            \
    bf[(QN)*2 + ni][1] = *(const bf16x8*)((P1) + ((QN)*2 + ni) * 2048);            \
  }

#define TILE3(APa, APb, BPa, BPb, SA1, SB0, SB1A0, WAIT)                           \
  {                                                                                \
    RDA2(APa, APb, 0); RDB2(BPa, BPb, 0); RDB2(BPa, BPb, 1);                       \
    SA1;                                                                           \
    LGKM8();                                                                       \
    BAR(); LGKM0();                                                                \
    PRIO1(); MFMA16(0, 0); MFMA16(0, 1); PRIO0();                                  \
    BAR();                                                                         \
    RDA2(APa, APb, 1);                                                             \
    SB0;                                                                           \
    BAR(); LGKM0();                                                                \
    PRIO1(); MFMA16(1, 0); PRIO0();                                                \
    BAR();                                                                         \
    SB1A0;                                                                         \
    WAIT();                                                                        \
    BAR(); LGKM0();                                                                \
    PRIO1(); MFMA16(1, 1); PRIO0();                                                \
    BAR();                                                                         \
  }

template <int MODE>
__global__ __launch_bounds__(512, 2) void k_gemm(const u16* __restrict__ A,
                                                 const u16* __restrict__ Bt,
                                                 void* __restrict__ Cout) {
  __shared__ __align__(16) u16 L[2][2][16384];
  const int tid = threadIdx.x;
  const int wid = tid >> 6, lane = tid & 63;
  const int g = lane >> 4, li = lane & 15;
  const int wr = wid >> 2, wc = wid & 3;

  const int bid = blockIdx.x;
  const int sw = ((bid & 7) << 5) | (bid >> 3);
  const int brow = (sw >> 4) * 256, bcol = (sw & 15) * 256;

  const int xsw = (li & 7) << 4;
  const int abase = (wr * 128 + li) * 128 + g * 16;
  const int bbase = (wc * 64 + li) * 128 + g * 16;

  const char* Lc = (const char*)&L[0][0][0];
  const char* aP00 = Lc + ((abase) ^ xsw);
  const char* aP01 = Lc + ((abase + 64) ^ xsw);
  const char* aP10 = Lc + 65536 + ((abase) ^ xsw);
  const char* aP11 = Lc + 65536 + ((abase + 64) ^ xsw);
  const char* bP00 = Lc + 32768 + ((bbase) ^ xsw);
  const char* bP01 = Lc + 32768 + ((bbase + 64) ^ xsw);
  const char* bP10 = Lc + 98304 + ((bbase) ^ xsw);
  const char* bP11 = Lc + 98304 + ((bbase + 64) ^ xsw);

  const int sxy = ((tid >> 3) & 7) << 3;
  const int scol = ((tid * 8) ^ sxy) & 63;
  const int srow0 = tid >> 3;
  const u16* gA0 = A + (size_t)(brow + srow0) * DD + scol;
  const u16* gA1 = A + (size_t)(brow + 128 + srow0) * DD + scol;
  const u16* gB0 = Bt + (size_t)(bcol + srow0) * DD + scol;
  const u16* gB1 = Bt + (size_t)(bcol + 128 + srow0) * DD + scol;
  u16* dA0b0 = &L[0][0][wid * 512];
  u16* dA1b0 = &L[0][0][8192 + wid * 512];
  u16* dB0b0 = &L[0][1][wid * 512];
  u16* dB1b0 = &L[0][1][8192 + wid * 512];
  u16* dA0b1 = &L[1][0][wid * 512];
  u16* dA1b1 = &L[1][0][8192 + wid * 512];
  u16* dB0b1 = &L[1][1][wid * 512];
  u16* dB1b1 = &L[1][1][8192 + wid * 512];

  auto SH = [&](const u16* gsrc, u16* ld) {
    gl_lds16(gsrc, ld);
    gl_lds16(gsrc + (size_t)64 * DD, ld + 4096);
  };

  f32x4 acc[8][4];
#pragma unroll
  for (int m = 0; m < 8; ++m)
#pragma unroll
    for (int n = 0; n < 4; ++n) acc[m][n] = zero4();

  bf16x8 af[4][2], bf[4][2];

  SH(gA0, dA0b0); SH(gA1, dA1b0); SH(gB0, dB0b0); SH(gB1, dB1b0);
  SH(gA0 + 64, dA0b1); SH(gB0 + 64, dB0b1); SH(gB1 + 64, dB1b1);
  VM6();
  BAR();

  for (int it = 0; it < 31; ++it) {
    const u16* a0 = gA0 + it * 128;
    const u16* a1 = gA1 + it * 128;
    const u16* b0 = gB0 + it * 128;
    const u16* b1 = gB1 + it * 128;
    TILE3(aP00, aP01, bP00, bP01,
          SH(a1 + 64, dA1b1),
          SH(b0 + 128, dB0b0),
          { SH(b1 + 128, dB1b0); SH(a0 + 128, dA0b0); },
          VM6);
    TILE3(aP10, aP11, bP10, bP11,
          SH(a1 + 128, dA1b0),
          SH(b0 + 192, dB0b1),
          { SH(b1 + 192, dB1b1); SH(a0 + 192, dA0b1); },
          VM6);
  }

  {
    const u16* a1 = gA1 + 31 * 128;
    TILE3(aP00, aP01, bP00, bP01,
          SH(a1 + 64, dA1b1),
          (void)0,
          (void)0,
          VM0);
  }
  TILE3(aP10, aP11, bP10, bP11, (void)0, (void)0, (void)0, LGKM0);

#pragma unroll
  for (int m = 0; m < 8; ++m) {
#pragma unroll
    for (int n = 0; n < 4; ++n) {
#pragma unroll
      for (int r = 0; r < 4; ++r) {
        int row = brow + wr * 128 + m * 16 + g * 4 + r;
        int col = bcol + wc * 64 + n * 16 + li;
        float v = acc[m][n][r];
        if (MODE == 0) {
          ((u16*)Cout)[(size_t)row * DD + col] = cvt1(v);
        } else if (MODE == 1) {
          ((u16*)Cout)[((size_t)((row >> 11) << 12) + col) * SS + (row & 2047)] = cvt1(v);
        } else {
          ((float*)Cout)[(size_t)row * DD + col] = v;
        }
      }
    }
  }
}

// ---------------- RoPE in-place on Q and K; Q pre-scaled by 1/sqrt(HD)*log2e ----------------
__global__ __launch_bounds__(256) void k_rope(u16* __restrict__ Q, u16* __restrict__ Kp,
                                              const float* __restrict__ fc,
                                              const float* __restrict__ fs) {
  int idx = blockIdx.x * blockDim.x + threadIdx.x;
  const int n8 = MM * DD / 8;
  const float qsc = idx < n8 ? 0.08838834764831845f * 1.44269504088896340f : 1.0f;
  u16* T = idx < n8 ? Q : Kp;
  int i = idx < n8 ? idx : idx - n8;
  int m = i >> 9;
  int c = (i & 511) * 8;
  int s = m & (SS - 1);
  int i0 = (c & (HDD - 1)) >> 1;
  size_t o = (size_t)m * DD + c;
  ushort8 v = *(ushort8*)(T + o);
  float4v cs = *(const float4v*)(fc + s * 64 + i0);
  float4v sn = *(const float4v*)(fs + s * 64 + i0);
  ushort8 ov;
#pragma unroll
  for (int p = 0; p < 4; ++p) {
    float a = bf2f(v[2 * p]), cc = bf2f(v[2 * p + 1]);
    ov[2 * p]     = cvt1((a * cs[p] - cc * sn[p]) * qsc);
    ov[2 * p + 1] = cvt1((a * sn[p] + cc * cs[p]) * qsc);
  }
  *(ushort8*)(T + o) = ov;
}

// ---------------- flash attention v10: QBLK=128, 8 waves + masked-tile skip ----------------
// v9 + per-wave skip of fully-masked diagonal tiles: wave w skips compute (exact:
// all its p == 0) when koff > w*16+15; barriers/staging/vmcnt stay unconditional.
__global__ __launch_bounds__(512) void k_attn(const u16* __restrict__ Q,
                                              const u16* __restrict__ K,
                                              const u16* __restrict__ VT,
                                              u16* __restrict__ O) {
  __shared__ __align__(16) u16 Kl[2][32 * 128];
  __shared__ __align__(16) u16 Vl[2][128 * 32];
  __shared__ __align__(16) u16 Pl[8][16 * 32];
  const int bh = blockIdx.x;       // fast dim -> (b,h) locality per XCD
  const int qt = 15 - blockIdx.y;  // heavy blocks dispatch first
  const int b = bh >> 5, h = bh & 31;
  const int tid = threadIdx.x, w = tid >> 6, lane = tid & 63;
  const int g = lane >> 4, li = lane & 15;

  const u16* Qbase = Q + ((size_t)(b * SS + qt * 128 + w * 16 + li)) * DD + h * HDD;
  const u16* Kbase = K + ((size_t)(b * SS)) * DD + h * HDD;
  const u16* Vbase = VT + ((size_t)bh) * HDD * SS;

  bf16x8 qf[4];
#pragma unroll
  for (int ks = 0; ks < 4; ++ks)
    qf[ks] = *(const bf16x8*)(Qbase + ks * 32 + g * 8);

  f32x4 oa[8];
#pragma unroll
  for (int f = 0; f < 8; ++f) oa[f] = zero4();
  float lrun = 0.f;  // denominator for q-row = w*16 + li (scaled 2^-16)
  const int wli = w * 16 + li;

  const int krow = w * 4 + (lane >> 4);
  const int ksg = (lane & 15) ^ (((w & 1) << 2) + (lane >> 4));
  const int vdr = w * 16 + (lane >> 2);
  const int va = (vdr * 64 + (lane & 3) * 16) ^ (((vdr >> 1) & 7) << 4);

  auto STAGE = [&](int t, int nb) {
    const u16* Kt = Kbase + (size_t)(t * 32) * DD;
    gl_lds16(Kt + (size_t)krow * DD + ksg * 8, &Kl[nb][(w * 4) * 128]);
    const u16* Vt = Vbase + t * 32;
    gl_lds16(Vt + (size_t)(va >> 6) * SS + ((va >> 4) & 3) * 8, &Vl[nb][w * 512]);
  };

  auto TILE = [&](int kt, int cb, int koff) __attribute__((always_inline)) {
    // per-wave exact skip: tile fully masked for this wave (all p == 0)
    if (!(koff >= 0 && koff > w * 16 + 15)) {
      f32x4 sc[2];
      sc[0] = zero4(); sc[1] = zero4();
      PRIO1();
#pragma unroll
      for (int ks = 0; ks < 4; ++ks) {
#pragma unroll
        for (int ktg = 0; ktg < 2; ++ktg) {
          int kr = ktg * 16 + li;
          int off = (kr * 256 + (ks * 32 + g * 8) * 2) ^ ((kr & 7) << 4);
          bf16x8 kf = *(const bf16x8*)((const char*)Kl[cb] + off);
          sc[ktg] = __builtin_amdgcn_mfma_f32_16x16x32_bf16(kf, qf[ks], sc[ktg], 0, 0, 0);
        }
      }
      PRIO0();

      // fixed-shift softmax: p = exp2(s - 16); no max tracking, no rescale
      float p[8];
      float su = 0.f;
#pragma unroll
      for (int ktg = 0; ktg < 2; ++ktg) {
#pragma unroll
        for (int r = 0; r < 4; ++r) {
          float s = sc[ktg][r];
          if (koff >= 0 && (koff + ktg * 16 + g * 4 + r > wli)) s = -1e30f;
          float pv = exp2a(s - 16.f);
          p[ktg * 4 + r] = pv;
          su += pv;
        }
      }
      su += __shfl_xor(su, 16);
      su += __shfl_xor(su, 32);
      lrun += su;

      {
        char* Pb = (char*)Pl[w];
        const int swz = ((li >> 1) & 7) << 4;
#pragma unroll
        for (int ktg = 0; ktg < 2; ++ktg) {
#pragma unroll
          for (int j = 0; j < 2; ++j) {
            unsigned pk = cvtpk(p[ktg * 4 + 2 * j], p[ktg * 4 + 2 * j + 1]);
            int off = (li * 64 + ktg * 32 + g * 8 + 4 * j) ^ swz;
            *(unsigned*)(Pb + off) = pk;
          }
        }
      }
      asm volatile("s_waitcnt lgkmcnt(0)" ::: "memory");

      PRIO1();
      {
        int poff = (li * 64 + g * 16) ^ (((li >> 1) & 7) << 4);
        bf16x8 pfrag = *(const bf16x8*)((const char*)Pl[w] + poff);
#pragma unroll
        for (int f = 0; f < 8; ++f) {
          int dr = f * 16 + li;
          int voff = (dr * 64 + g * 16) ^ (((dr >> 1) & 7) << 4);
          bf16x8 vf = *(const bf16x8*)((const char*)Vl[cb] + voff);
          oa[f] = __builtin_amdgcn_mfma_f32_16x16x32_bf16(pfrag, vf, oa[f], 0, 0, 0);
        }
      }
      PRIO0();
    }

    asm volatile("s_waitcnt vmcnt(0)" ::: "memory");  // next tile's DMA landed
    __syncthreads();                                  // all waves done with buf cb
  };

  STAGE(0, 0);
  asm volatile("s_waitcnt vmcnt(0)" ::: "memory");
  __syncthreads();

  for (int i = 0; i < 2 * qt; ++i) {
    STAGE(2 * i + 1, 1);
    TILE(2 * i, 0, -1);
    STAGE(2 * i + 2, 0);
    TILE(2 * i + 1, 1, -1);
  }
  const int d0 = 4 * qt;
  STAGE(d0 + 1, 1);
  TILE(d0, 0, 0);
  STAGE(d0 + 2, 0);
  TILE(d0 + 1, 1, 32);
  STAGE(d0 + 3, 1);
  TILE(d0 + 2, 0, 64);
  TILE(d0 + 3, 1, 96);

  float lv[4];
#pragma unroll
  for (int r = 0; r < 4; ++r) lv[r] = __shfl(lrun, g * 20 + r);
  u16* Ob = O + ((size_t)(b * SS + qt * 128 + w * 16 + g * 4)) * DD + h * HDD;
#pragma unroll
  for (int r = 0; r < 4; ++r) {
    float inv = 1.f / lv[r];
#pragma unroll
    for (int f = 0; f < 8; ++f)
      Ob[(size_t)r * DD + f * 16 + li] = cvt1(oa[f][r] * inv);
  }
}

// ---------------- host ----------------
extern "C" void kernel_launch(void* const* d_in, const int* in_sizes, int n_in,
                              void* d_out, int out_size, void* d_ws, size_t ws_size,
                              hipStream_t stream) {
  (void)in_sizes; (void)n_in; (void)out_size; (void)ws_size;
  const float* x    = (const float*)d_in[0];
  const float* Wq   = (const float*)d_in[1];
  const float* Wk   = (const float*)d_in[2];
  const float* Wv   = (const float*)d_in[3];
  const float* Wo   = (const float*)d_in[4];
  const float* fcos = (const float*)d_in[5];
  const float* fsin = (const float*)d_in[6];

  u16* ws = (u16*)d_ws;
  const size_t MAT = (size_t)4096 * 4096;
  u16* xb    = ws + 0 * MAT;
  u16* wqt   = ws + 1 * MAT;
  u16* wkt   = ws + 2 * MAT;
  u16* wvt   = ws + 3 * MAT;
  u16* wot   = ws + 4 * MAT;
  u16* Qb    = ws + 5 * MAT;
  u16* Kb    = ws + 6 * MAT;
  u16* VTb   = ws + 7 * MAT;
  u16* attnb = ws + 8 * MAT;

  k_prep<<<dim3(64, 64, 5), dim3(64, 4), 0, stream>>>(x, Wq, Wk, Wv, Wo, xb, wqt);
  k_gemm<0><<<dim3(256), dim3(512), 0, stream>>>(xb, wqt, (void*)Qb);
  k_gemm<0><<<dim3(256), dim3(512), 0, stream>>>(xb, wkt, (void*)Kb);
  k_gemm<1><<<dim3(256), dim3(512), 0, stream>>>(xb, wvt, (void*)VTb);
  k_rope<<<dim3(16384), dim3(256), 0, stream>>>(Qb, Kb, fcos, fsin);
  k_attn<<<dim3(64, 16), dim3(512), 0, stream>>>(Qb, Kb, VTb, attnb);
  k_gemm<2><<<dim3(256), dim3(512), 0, stream>>>(attnb, wot, d_out);
}

// Round 20
// 722.806 us; speedup vs baseline: 1.0453x; 1.0453x over previous
//
#include <hip/hip_runtime.h>
#include <hip/hip_bf16.h>

#define DD 4096
#define MM 4096
#define SS 2048
#define HH 32
#define HDD 128
#define NT 64  // BK=64 K-tiles

typedef unsigned short u16;
typedef unsigned int u32;
typedef __attribute__((ext_vector_type(8))) __bf16 bf16x8;
typedef __attribute__((ext_vector_type(4))) float f32x4;
typedef __attribute__((ext_vector_type(4))) float float4v;
typedef __attribute__((ext_vector_type(8))) unsigned short ushort8;
typedef __attribute__((ext_vector_type(4))) unsigned int uint4v;

__device__ __forceinline__ u16 f2bf(float f) {
  union { float f; unsigned u; } v; v.f = f;
  unsigned u = v.u;
  return (u16)((u + 0x7fffu + ((u >> 16) & 1u)) >> 16);
}
__device__ __forceinline__ float bf2f(u16 s) {
  union { unsigned u; float f; } v; v.u = ((unsigned)s) << 16;
  return v.f;
}
__device__ __forceinline__ f32x4 zero4() { f32x4 z = {0.f, 0.f, 0.f, 0.f}; return z; }

__device__ __forceinline__ void gl_lds16(const u16* g, u16* l) {
  __builtin_amdgcn_global_load_lds((__attribute__((address_space(1))) void*)(g),
                                   (__attribute__((address_space(3))) void*)(l), 16, 0, 0);
}

__device__ __forceinline__ unsigned cvtpk(float lo, float hi) {
  unsigned r;
  asm("v_cvt_pk_bf16_f32 %0, %1, %2" : "=v"(r) : "v"(lo), "v"(hi));
  return r;
}
__device__ __forceinline__ u16 cvt1(float v) {
  unsigned r;
  asm("v_cvt_pk_bf16_f32 %0, %1, %1" : "=v"(r) : "v"(v));
  return (u16)r;
}
__device__ __forceinline__ float exp2a(float x) {
  float r;
  asm("v_exp_f32 %0, %1" : "=v"(r) : "v"(x));
  return r;
}

// ---------------- f32 -> bf16 convert (x) ----------------
__global__ __launch_bounds__(256) void k_cvt(const float* __restrict__ in,
                                             u16* __restrict__ out, int n8) {
  int i = blockIdx.x * blockDim.x + threadIdx.x;
  if (i >= n8) return;
  size_t o = (size_t)i * 8;
  float4v a = *(const float4v*)(in + o);
  float4v b = *(const float4v*)(in + o + 4);
  ushort8 v;
  v[0] = f2bf(a[0]); v[1] = f2bf(a[1]); v[2] = f2bf(a[2]); v[3] = f2bf(a[3]);
  v[4] = f2bf(b[0]); v[5] = f2bf(b[1]); v[6] = f2bf(b[2]); v[7] = f2bf(b[3]);
  *(ushort8*)(out + o) = v;
}

// ---------------- weight transpose + convert: out[n][k] = W[k][n] ----------------
__global__ __launch_bounds__(256) void k_wt(const float* __restrict__ W0,
                                            const float* __restrict__ W1,
                                            const float* __restrict__ W2,
                                            const float* __restrict__ W3,
                                            u16* __restrict__ out) {
  const float* W = blockIdx.z == 0 ? W0 : blockIdx.z == 1 ? W1 : blockIdx.z == 2 ? W2 : W3;
  u16* O = out + (size_t)blockIdx.z * DD * DD;
  __shared__ u16 t[64][66];
  int k0 = blockIdx.x * 64, n0 = blockIdx.y * 64;
  int tx = threadIdx.x, ty = threadIdx.y;  // (64,4)
#pragma unroll
  for (int i = 0; i < 16; ++i) {
    int kk = ty + i * 4;
    t[tx][kk] = cvt1(W[(size_t)(k0 + kk) * DD + n0 + tx]);
  }
  __syncthreads();
  const int L = ty * 64 + tx;
  const int kx = L & 31, nb = L >> 5;
#pragma unroll
  for (int i = 0; i < 8; ++i) {
    int nn = nb + i * 8;
    u32 pk = *(const u32*)&t[nn][2 * kx];
    *(u32*)&O[(size_t)(n0 + nn) * DD + k0 + 2 * kx] = pk;
  }
}

#define BAR() __builtin_amdgcn_s_barrier()
#define LGKM0() asm volatile("s_waitcnt lgkmcnt(0)" ::: "memory")
#define LGKM8() asm volatile("s_waitcnt lgkmcnt(8)" ::: "memory")
#define VM6() asm volatile("s_waitcnt vmcnt(6)" ::: "memory")
#define VM0() asm volatile("s_waitcnt vmcnt(0)" ::: "memory")
#define PRIO1() __builtin_amdgcn_s_setprio(1)
#define PRIO0() __builtin_amdgcn_s_setprio(0)

// ---------------- 256x256 BK=64 deep-staged GEMM (r12/r17, 3-phase tiles) ----------------
#define MFMA16(QM, QN)                                                             \
  _Pragma("unroll") for (int kk = 0; kk < 2; ++kk)                                 \
  _Pragma("unroll") for (int mi = 0; mi < 4; ++mi)                                 \
  _Pragma("unroll") for (int ni = 0; ni < 2; ++ni)                                 \
      acc[(QM)*4 + mi][(QN)*2 + ni] = __builtin_amdgcn_mfma_f32_16x16x32_bf16(     \
          af[mi][kk], bf[(QN)*2 + ni][kk], acc[(QM)*4 + mi][(QN)*2 + ni], 0, 0, 0);

#define RDA2(P0, P1, QM)                                                           \
  _Pragma("unroll") for (int mi = 0; mi < 4; ++mi) {                               \
    af[mi][0] = *(const bf16x8*)((P0) + ((QM)*4 + mi) * 2048);                     \
    af[mi][1] = *(const bf16x8*)((P1) + ((QM)*4 + mi) * 2048);                     \
  }

#define RDB2(P0, P1, QN)                                                           \
  _Pragma("unroll") for (int ni = 0; ni < 2; ++ni) {                               \
    bf[(QN)*2 + ni][0] = *(const bf16x8*)((P0) + ((QN)*2 + ni) * 2048);            \
    bf[(QN)*2 + ni][1] = *(const bf16x8*)((P1) + ((QN)*2 + ni) * 2048);            \
  }

#define TILE3(APa, APb, BPa, BPb, SA1, SB0, SB1A0, WAIT)                           \
  {                                                                                \
    RDA2(APa, APb, 0); RDB2(BPa, BPb, 0); RDB2(BPa, BPb, 1);                       \
    SA1;                                                                           \
    LGKM8();                                                                       \
    BAR(); LGKM0();                                                                \
    PRIO1(); MFMA16(0, 0); MFMA16(0, 1); PRIO0();                                  \
    BAR();                                                                         \
    RDA2(APa, APb, 1);                                                             \
    SB0;                                                                           \
    BAR(); LGKM0();                                                                \
    PRIO1(); MFMA16(1, 0); PRIO0();                                                \
    BAR();                                                                         \
    SB1A0;                                                                         \
    WAIT();                                                                        \
    BAR(); LGKM0();                                                                \
    PRIO1(); MFMA16(1, 1); PRIO0();                                                \
    BAR();                                                                         \
  }

template <int MODE>
__global__ __launch_bounds__(512, 2) void k_gemm(const u16* __restrict__ A,
                                                 const u16* __restrict__ Bt,
                                                 void* __restrict__ Cout) {
  __shared__ __align__(16) u16 L[2][2][16384];
  const int tid = threadIdx.x;
  const int wid = tid >> 6, lane = tid & 63;
  const int g = lane >> 4, li = lane & 15;
  const int wr = wid >> 2, wc = wid & 3;

  const int bid = blockIdx.x;
  const int sw = ((bid & 7) << 5) | (bid >> 3);
  const int brow = (sw >> 4) * 256, bcol = (sw & 15) * 256;

  const int xsw = (li & 7) << 4;
  const int abase = (wr * 128 + li) * 128 + g * 16;
  const int bbase = (wc * 64 + li) * 128 + g * 16;

  const char* Lc = (const char*)&L[0][0][0];
  const char* aP00 = Lc + ((abase) ^ xsw);
  const char* aP01 = Lc + ((abase + 64) ^ xsw);
  const char* aP10 = Lc + 65536 + ((abase) ^ xsw);
  const char* aP11 = Lc + 65536 + ((abase + 64) ^ xsw);
  const char* bP00 = Lc + 32768 + ((bbase) ^ xsw);
  const char* bP01 = Lc + 32768 + ((bbase + 64) ^ xsw);
  const char* bP10 = Lc + 98304 + ((bbase) ^ xsw);
  const char* bP11 = Lc + 98304 + ((bbase + 64) ^ xsw);

  const int sxy = ((tid >> 3) & 7) << 3;
  const int scol = ((tid * 8) ^ sxy) & 63;
  const int srow0 = tid >> 3;
  const u16* gA0 = A + (size_t)(brow + srow0) * DD + scol;
  const u16* gA1 = A + (size_t)(brow + 128 + srow0) * DD + scol;
  const u16* gB0 = Bt + (size_t)(bcol + srow0) * DD + scol;
  const u16* gB1 = Bt + (size_t)(bcol + 128 + srow0) * DD + scol;
  u16* dA0b0 = &L[0][0][wid * 512];
  u16* dA1b0 = &L[0][0][8192 + wid * 512];
  u16* dB0b0 = &L[0][1][wid * 512];
  u16* dB1b0 = &L[0][1][8192 + wid * 512];
  u16* dA0b1 = &L[1][0][wid * 512];
  u16* dA1b1 = &L[1][0][8192 + wid * 512];
  u16* dB0b1 = &L[1][1][wid * 512];
  u16* dB1b1 = &L[1][1][8192 + wid * 512];

  auto SH = [&](const u16* gsrc, u16* ld) {
    gl_lds16(gsrc, ld);
    gl_lds16(gsrc + (size_t)64 * DD, ld + 4096);
  };

  f32x4 acc[8][4];
#pragma unroll
  for (int m = 0; m < 8; ++m)
#pragma unroll
    for (int n = 0; n < 4; ++n) acc[m][n] = zero4();

  bf16x8 af[4][2], bf[4][2];

  SH(gA0, dA0b0); SH(gA1, dA1b0); SH(gB0, dB0b0); SH(gB1, dB1b0);
  SH(gA0 + 64, dA0b1); SH(gB0 + 64, dB0b1); SH(gB1 + 64, dB1b1);
  VM6();
  BAR();

  for (int it = 0; it < 31; ++it) {
    const u16* a0 = gA0 + it * 128;
    const u16* a1 = gA1 + it * 128;
    const u16* b0 = gB0 + it * 128;
    const u16* b1 = gB1 + it * 128;
    TILE3(aP00, aP01, bP00, bP01,
          SH(a1 + 64, dA1b1),
          SH(b0 + 128, dB0b0),
          { SH(b1 + 128, dB1b0); SH(a0 + 128, dA0b0); },
          VM6);
    TILE3(aP10, aP11, bP10, bP11,
          SH(a1 + 128, dA1b0),
          SH(b0 + 192, dB0b1),
          { SH(b1 + 192, dB1b1); SH(a0 + 192, dA0b1); },
          VM6);
  }

  {
    const u16* a1 = gA1 + 31 * 128;
    TILE3(aP00, aP01, bP00, bP01,
          SH(a1 + 64, dA1b1),
          (void)0,
          (void)0,
          VM0);
  }
  TILE3(aP10, aP11, bP10, bP11, (void)0, (void)0, (void)0, LGKM0);

#pragma unroll
  for (int m = 0; m < 8; ++m) {
#pragma unroll
    for (int n = 0; n < 4; ++n) {
#pragma unroll
      for (int r = 0; r < 4; ++r) {
        int row = brow + wr * 128 + m * 16 + g * 4 + r;
        int col = bcol + wc * 64 + n * 16 + li;
        float v = acc[m][n][r];
        if (MODE == 0) {
          ((u16*)Cout)[(size_t)row * DD + col] = cvt1(v);
        } else if (MODE == 1) {
          ((u16*)Cout)[((size_t)((row >> 11) << 12) + col) * SS + (row & 2047)] = cvt1(v);
        } else {
          ((float*)Cout)[(size_t)row * DD + col] = v;
        }
      }
    }
  }
}

// ---------------- RoPE in-place on Q and K; Q pre-scaled by 1/sqrt(HD)*log2e ----------------
__global__ __launch_bounds__(256) void k_rope(u16* __restrict__ Q, u16* __restrict__ Kp,
                                              const float* __restrict__ fc,
                                              const float* __restrict__ fs) {
  int idx = blockIdx.x * blockDim.x + threadIdx.x;
  const int n8 = MM * DD / 8;
  const float qsc = idx < n8 ? 0.08838834764831845f * 1.44269504088896340f : 1.0f;
  u16* T = idx < n8 ? Q : Kp;
  int i = idx < n8 ? idx : idx - n8;
  int m = i >> 9;
  int c = (i & 511) * 8;
  int s = m & (SS - 1);
  int i0 = (c & (HDD - 1)) >> 1;
  size_t o = (size_t)m * DD + c;
  ushort8 v = *(ushort8*)(T + o);
  float4v cs = *(const float4v*)(fc + s * 64 + i0);
  float4v sn = *(const float4v*)(fs + s * 64 + i0);
  ushort8 ov;
#pragma unroll
  for (int p = 0; p < 4; ++p) {
    float a = bf2f(v[2 * p]), cc = bf2f(v[2 * p + 1]);
    ov[2 * p]     = cvt1((a * cs[p] - cc * sn[p]) * qsc);
    ov[2 * p + 1] = cvt1((a * sn[p] + cc * cs[p]) * qsc);
  }
  *(ushort8*)(T + o) = ov;
}

// ---------------- flash attention v9: QBLK=128 via 8 waves (r18, best) ----------------
__global__ __launch_bounds__(512) void k_attn(const u16* __restrict__ Q,
                                              const u16* __restrict__ K,
                                              const u16* __restrict__ VT,
                                              u16* __restrict__ O) {
  __shared__ __align__(16) u16 Kl[2][32 * 128];
  __shared__ __align__(16) u16 Vl[2][128 * 32];
  __shared__ __align__(16) u16 Pl[8][16 * 32];
  const int bh = blockIdx.x;       // fast dim -> (b,h) locality per XCD
  const int qt = 15 - blockIdx.y;  // heavy blocks dispatch first
  const int b = bh >> 5, h = bh & 31;
  const int tid = threadIdx.x, w = tid >> 6, lane = tid & 63;
  const int g = lane >> 4, li = lane & 15;

  const u16* Qbase = Q + ((size_t)(b * SS + qt * 128 + w * 16 + li)) * DD + h * HDD;
  const u16* Kbase = K + ((size_t)(b * SS)) * DD + h * HDD;
  const u16* Vbase = VT + ((size_t)bh) * HDD * SS;

  bf16x8 qf[4];
#pragma unroll
  for (int ks = 0; ks < 4; ++ks)
    qf[ks] = *(const bf16x8*)(Qbase + ks * 32 + g * 8);

  f32x4 oa[8];
#pragma unroll
  for (int f = 0; f < 8; ++f) oa[f] = zero4();
  float lrun = 0.f;  // denominator for q-row = w*16 + li (scaled 2^-16)
  const int wli = w * 16 + li;

  const int krow = w * 4 + (lane >> 4);
  const int ksg = (lane & 15) ^ (((w & 1) << 2) + (lane >> 4));
  const int vdr = w * 16 + (lane >> 2);
  const int va = (vdr * 64 + (lane & 3) * 16) ^ (((vdr >> 1) & 7) << 4);

  auto STAGE = [&](int t, int nb) {
    const u16* Kt = Kbase + (size_t)(t * 32) * DD;
    gl_lds16(Kt + (size_t)krow * DD + ksg * 8, &Kl[nb][(w * 4) * 128]);
    const u16* Vt = Vbase + t * 32;
    gl_lds16(Vt + (size_t)(va >> 6) * SS + ((va >> 4) & 3) * 8, &Vl[nb][w * 512]);
  };

  auto TILE = [&](int kt, int cb, int koff) __attribute__((always_inline)) {
    f32x4 sc[2];
    sc[0] = zero4(); sc[1] = zero4();
    PRIO1();
#pragma unroll
    for (int ks = 0; ks < 4; ++ks) {
#pragma unroll
      for (int ktg = 0; ktg < 2; ++ktg) {
        int kr = ktg * 16 + li;
        int off = (kr * 256 + (ks * 32 + g * 8) * 2) ^ ((kr & 7) << 4);
        bf16x8 kf = *(const bf16x8*)((const char*)Kl[cb] + off);
        sc[ktg] = __builtin_amdgcn_mfma_f32_16x16x32_bf16(kf, qf[ks], sc[ktg], 0, 0, 0);
      }
    }
    PRIO0();

    // fixed-shift softmax: p = exp2(s - 16); no max tracking, no rescale
    float p[8];
    float su = 0.f;
#pragma unroll
    for (int ktg = 0; ktg < 2; ++ktg) {
#pragma unroll
      for (int r = 0; r < 4; ++r) {
        float s = sc[ktg][r];
        if (koff >= 0 && (koff + ktg * 16 + g * 4 + r > wli)) s = -1e30f;
        float pv = exp2a(s - 16.f);
        p[ktg * 4 + r] = pv;
        su += pv;
      }
    }
    su += __shfl_xor(su, 16);
    su += __shfl_xor(su, 32);
    lrun += su;

    {
      char* Pb = (char*)Pl[w];
      const int swz = ((li >> 1) & 7) << 4;
#pragma unroll
      for (int ktg = 0; ktg < 2; ++ktg) {
#pragma unroll
        for (int j = 0; j < 2; ++j) {
          unsigned pk = cvtpk(p[ktg * 4 + 2 * j], p[ktg * 4 + 2 * j + 1]);
          int off = (li * 64 + ktg * 32 + g * 8 + 4 * j) ^ swz;
          *(unsigned*)(Pb + off) = pk;
        }
      }
    }
    asm volatile("s_waitcnt lgkmcnt(0)" ::: "memory");

    PRIO1();
    {
      int poff = (li * 64 + g * 16) ^ (((li >> 1) & 7) << 4);
      bf16x8 pfrag = *(const bf16x8*)((const char*)Pl[w] + poff);
#pragma unroll
      for (int f = 0; f < 8; ++f) {
        int dr = f * 16 + li;
        int voff = (dr * 64 + g * 16) ^ (((dr >> 1) & 7) << 4);
        bf16x8 vf = *(const bf16x8*)((const char*)Vl[cb] + voff);
        oa[f] = __builtin_amdgcn_mfma_f32_16x16x32_bf16(pfrag, vf, oa[f], 0, 0, 0);
      }
    }
    PRIO0();

    asm volatile("s_waitcnt vmcnt(0)" ::: "memory");  // next tile's DMA landed
    __syncthreads();                                  // all waves done with buf cb
  };

  STAGE(0, 0);
  asm volatile("s_waitcnt vmcnt(0)" ::: "memory");
  __syncthreads();

  // unmasked pairs: tiles 0 .. 4qt-1
  for (int i = 0; i < 2 * qt; ++i) {
    STAGE(2 * i + 1, 1);
    TILE(2 * i, 0, -1);
    STAGE(2 * i + 2, 0);
    TILE(2 * i + 1, 1, -1);
  }
  // diagonal region: tiles 4qt .. 4qt+3, compile-time koff = 32j
  const int d0 = 4 * qt;
  STAGE(d0 + 1, 1);
  TILE(d0, 0, 0);
  STAGE(d0 + 2, 0);
  TILE(d0 + 1, 1, 32);
  STAGE(d0 + 3, 1);
  TILE(d0 + 2, 0, 64);
  TILE(d0 + 3, 1, 96);

  // epilogue: O rows q = g*4 + r; fetch l from the lane owning that q
  float lv[4];
#pragma unroll
  for (int r = 0; r < 4; ++r) lv[r] = __shfl(lrun, g * 20 + r);
  u16* Ob = O + ((size_t)(b * SS + qt * 128 + w * 16 + g * 4)) * DD + h * HDD;
#pragma unroll
  for (int r = 0; r < 4; ++r) {
    float inv = 1.f / lv[r];
#pragma unroll
    for (int f = 0; f < 8; ++f)
      Ob[(size_t)r * DD + f * 16 + li] = cvt1(oa[f][r] * inv);
  }
}

// ---------------- host ----------------
extern "C" void kernel_launch(void* const* d_in, const int* in_sizes, int n_in,
                              void* d_out, int out_size, void* d_ws, size_t ws_size,
                              hipStream_t stream) {
  (void)in_sizes; (void)n_in; (void)out_size; (void)ws_size;
  const float* x    = (const float*)d_in[0];
  const float* Wq   = (const float*)d_in[1];
  const float* Wk   = (const float*)d_in[2];
  const float* Wv   = (const float*)d_in[3];
  const float* Wo   = (const float*)d_in[4];
  const float* fcos = (const float*)d_in[5];
  const float* fsin = (const float*)d_in[6];

  u16* ws = (u16*)d_ws;
  const size_t MAT = (size_t)4096 * 4096;
  u16* xb    = ws + 0 * MAT;
  u16* wqt   = ws + 1 * MAT;
  u16* wkt   = ws + 2 * MAT;
  u16* wvt   = ws + 3 * MAT;
  u16* wot   = ws + 4 * MAT;
  u16* Qb    = ws + 5 * MAT;
  u16* Kb    = ws + 6 * MAT;
  u16* VTb   = ws + 7 * MAT;
  u16* attnb = ws + 8 * MAT;

  k_cvt<<<dim3(8192), dim3(256), 0, stream>>>(x, xb, (int)(MAT / 8));
  k_wt<<<dim3(64, 64, 4), dim3(64, 4), 0, stream>>>(Wq, Wk, Wv, Wo, wqt);
  k_gemm<0><<<dim3(256), dim3(512), 0, stream>>>(xb, wqt, (void*)Qb);
  k_gemm<0><<<dim3(256), dim3(512), 0, stream>>>(xb, wkt, (void*)Kb);
  k_gemm<1><<<dim3(256), dim3(512), 0, stream>>>(xb, wvt, (void*)VTb);
  k_rope<<<dim3(16384), dim3(256), 0, stream>>>(Qb, Kb, fcos, fsin);
  k_attn<<<dim3(64, 16), dim3(512), 0, stream>>>(Qb, Kb, VTb, attnb);
  k_gemm<2><<<dim3(256), dim3(512), 0, stream>>>(attnb, wot, d_out);
}